// Round 2
// baseline (584.422 us; speedup 1.0000x reference)
//
#include <hip/hip_runtime.h>
#include <math.h>

// Problem constants (fixed by reference setup_inputs)
#define N_NODES 100000
#define N_INCID 2000000
#define HIDDEN  128
#define N_HE    100000

#define SCAN_B 1024
#define NB ((N_HE + SCAN_B - 1) / SCAN_B)   // 98

// ---------------- Pass 1: per-node scores  ns[n] = dot(feats[n], W) ----------
__global__ void node_scores_kernel(const float* __restrict__ nf,
                                   const float* __restrict__ W,
                                   float* __restrict__ ns) {
    int wave = threadIdx.x >> 6;
    int lane = threadIdx.x & 63;
    int n = blockIdx.x * 4 + wave;
    if (n >= N_NODES) return;
    const float2* nf2 = (const float2*)nf;
    const float2* w2  = (const float2*)W;
    float2 v = nf2[(size_t)n * 64 + lane];
    float2 w = w2[lane];
    float p = v.x * w.x + v.y * w.y;
    #pragma unroll
    for (int o = 32; o > 0; o >>= 1) p += __shfl_xor(p, o, 64);
    if (lane == 0) ns[n] = p;
}

// ---------------- Pass 2: histogram of incidences per hyperedge --------------
// NOTE: harness passes integer inputs as int32 (int64 in reference is cast).
__global__ void count_kernel(const int* __restrict__ he_idx,
                             int* __restrict__ counts) {
    int e = blockIdx.x * blockDim.x + threadIdx.x;
    if (e >= N_INCID) return;
    atomicAdd(&counts[he_idx[e]], 1);
}

// ---------------- Pass 3: exclusive scan (block scan + block-sum scan) -------
__global__ void scan1_kernel(const int* __restrict__ counts,
                             int* __restrict__ offsets,
                             int* __restrict__ blockSums) {
    __shared__ int s[SCAN_B];
    int t = threadIdx.x;
    int i = blockIdx.x * SCAN_B + t;
    int v = (i < N_HE) ? counts[i] : 0;
    s[t] = v;
    __syncthreads();
    for (int d = 1; d < SCAN_B; d <<= 1) {
        int x = (t >= d) ? s[t - d] : 0;
        __syncthreads();
        s[t] += x;
        __syncthreads();
    }
    if (i < N_HE) offsets[i] = s[t] - v;           // exclusive within block
    if (t == SCAN_B - 1) blockSums[blockIdx.x] = s[t];
}

__global__ void scan2_kernel(int* blockSums) {
    if (threadIdx.x == 0 && blockIdx.x == 0) {
        int run = 0;
        for (int i = 0; i < NB; ++i) { int v = blockSums[i]; blockSums[i] = run; run += v; }
    }
}

__global__ void scan3_kernel(int* __restrict__ offsets,
                             const int* __restrict__ blockSums,
                             int* __restrict__ cursor) {
    int i = blockIdx.x * SCAN_B + threadIdx.x;
    if (i >= N_HE) return;
    int o = offsets[i] + blockSums[blockIdx.x];
    offsets[i] = o;
    cursor[i] = o;
}

// ---------------- Pass 4: fill CSR node lists --------------------------------
__global__ void fill_kernel(const int* __restrict__ idx,
                            int* __restrict__ cursor,
                            int* __restrict__ csr) {
    int e = blockIdx.x * blockDim.x + threadIdx.x;
    if (e >= N_INCID) return;
    int he = idx[N_INCID + e];        // row 1: hyperedge ids
    int nd = idx[e];                  // row 0: node ids
    int pos = atomicAdd(&cursor[he], 1);
    csr[pos] = nd;
}

// ---------------- Pass 5: per-hyperedge softmax + weighted sum ---------------
// One wave per hyperedge; each lane owns 2 output columns (float2).
__global__ void compute_kernel(const int* __restrict__ offsets,
                               const int* __restrict__ counts,
                               const int* __restrict__ csr,
                               const float* __restrict__ ns,
                               const float* __restrict__ nf,
                               float* __restrict__ out) {
    int wave = threadIdx.x >> 6;
    int lane = threadIdx.x & 63;
    int he = blockIdx.x * 4 + wave;
    if (he >= N_HE) return;
    int beg = offsets[he];
    int deg = counts[he];
    float2 acc = make_float2(0.f, 0.f);
    if (deg > 0) {
        // segment max
        float m = -INFINITY;
        for (int j = lane; j < deg; j += 64)
            m = fmaxf(m, ns[csr[beg + j]]);
        #pragma unroll
        for (int o = 32; o > 0; o >>= 1) m = fmaxf(m, __shfl_xor(m, o, 64));
        // segment denom
        float dsum = 0.f;
        for (int j = lane; j < deg; j += 64)
            dsum += __expf(ns[csr[beg + j]] - m);
        #pragma unroll
        for (int o = 32; o > 0; o >>= 1) dsum += __shfl_xor(dsum, o, 64);
        float inv = 1.0f / fmaxf(dsum, 1e-20f);
        // weighted accumulation; lane reads a coalesced float2 of the node row
        const float2* nf2 = (const float2*)nf;
        for (int j = 0; j < deg; ++j) {
            int nd = csr[beg + j];                    // broadcast load
            float wj = __expf(ns[nd] - m) * inv;      // broadcast + cheap exp
            float2 v = nf2[(size_t)nd * 64 + lane];
            acc.x += wj * v.x;
            acc.y += wj * v.y;
        }
    }
    ((float2*)out)[(size_t)he * 64 + lane] = acc;     // empty hyperedges -> 0
}

extern "C" void kernel_launch(void* const* d_in, const int* in_sizes, int n_in,
                              void* d_out, int out_size, void* d_ws, size_t ws_size,
                              hipStream_t stream) {
    const float* nf  = (const float*)d_in[0];
    const int*   idx = (const int*)d_in[1];   // int32! harness downcasts int64
    // d_in[2] = num_hyperedges (device scalar) — fixed at 100000 by the reference.
    const float* W   = (const float*)d_in[3];
    float* out = (float*)d_out;

    char* ws = (char*)d_ws;
    float* ns        = (float*)(ws + 0);          // 100000 f32  (400000 B)
    int*   counts    = (int*)(ws + 400000);       // 100000 i32
    int*   offsets   = (int*)(ws + 800000);       // 100000 i32
    int*   cursor    = (int*)(ws + 1200000);      // 100000 i32
    int*   blockSums = (int*)(ws + 1600000);      // 128 i32
    int*   csr       = (int*)(ws + 1600512);      // 2000000 i32 (8 MB)

    hipMemsetAsync(counts, 0, N_HE * sizeof(int), stream);

    node_scores_kernel<<<(N_NODES + 3) / 4, 256, 0, stream>>>(nf, W, ns);
    count_kernel<<<(N_INCID + 255) / 256, 256, 0, stream>>>(idx + N_INCID, counts);
    scan1_kernel<<<NB, SCAN_B, 0, stream>>>(counts, offsets, blockSums);
    scan2_kernel<<<1, 64, 0, stream>>>(blockSums);
    scan3_kernel<<<NB, SCAN_B, 0, stream>>>(offsets, blockSums, cursor);
    fill_kernel<<<(N_INCID + 255) / 256, 256, 0, stream>>>(idx, cursor, csr);
    compute_kernel<<<(N_HE + 3) / 4, 256, 0, stream>>>(offsets, counts, csr, ns, nf, out);
}